// Round 7
// baseline (1659.058 us; speedup 1.0000x reference)
//
#include <hip/hip_runtime.h>

typedef __bf16 bf16x8 __attribute__((ext_vector_type(8)));
typedef float  f32x4  __attribute__((ext_vector_type(4)));

#define KDIM 2048
#define NDIM 8192
#define MTOT 32768
#define BM 256
#define BN 256
#define BK 64
#define NT 32            // K-tiles per output tile
#define NMT 131          // grouped 256-row m-tiles

__device__ __forceinline__ void gload_lds16(const void* g, void* l) {
    __builtin_amdgcn_global_load_lds(
        (const __attribute__((address_space(1))) void*)g,
        (__attribute__((address_space(3))) void*)l, 16, 0, 0);
}

// ---------------- fp32 -> bf16 pre-pass ----------------
__global__ __launch_bounds__(256) void convert_f32_bf16(
    const float* __restrict__ src, __bf16* __restrict__ dst, int n8)
{
    const int stride = gridDim.x * blockDim.x;
    for (int i = blockIdx.x * blockDim.x + threadIdx.x; i < n8; i += stride) {
        const f32x4* p = (const f32x4*)(src + (size_t)i * 8);
        f32x4 a = p[0], b = p[1];
        bf16x8 h;
        #pragma unroll
        for (int j = 0; j < 4; ++j) { h[j] = (__bf16)a[j]; h[4 + j] = (__bf16)b[j]; }
        *(bf16x8*)(dst + (size_t)i * 8) = h;
    }
}

// ---------------- persistent 256x256 8-phase grouped GEMM ----------------
// R6 (fixed compile): grid = 256 persistent blocks (1/CU). Each block sweeps
// tiles (mt = t*8 + bid%8, nt = bid/8). The double-buffer vmcnt(6) ring NEVER
// drains: at iter 15 the clamped re-stages are redirected to the NEXT tile's
// K-tiles 0/1, so a new tile starts with its pipeline already full. Epilogue
// stores between tiles inflate vmcnt; the next tile's first vmcnt(6) then
// over-drains once (bounded cost, not a hazard).
__global__ void __launch_bounds__(512, 2) moe_gemm_pers(
    const __bf16* __restrict__ A,   // [32768][2048] bf16
    const __bf16* __restrict__ W,   // [8][8192][2048] bf16
    float* __restrict__ C)          // [32768][8192] fp32
{
    __shared__ __bf16 As[2][BM * BK];   // 2 x 32 KiB
    __shared__ __bf16 Bs[2][BN * BK];   // 2 x 32 KiB

    const int tstart[9] = {0, 12, 32, 48, 56, 80, 96, 115, 131};
    const int offs[9]   = {0, 3000, 8000, 12096, 14144, 20144, 24144, 28768, 32768};

    const int xslot = blockIdx.x & 7;    // XCD slot: same-XCD blocks share mt
    const int ntb   = blockIdx.x >> 3;   // 0..31
    const int col0  = ntb * BN;

    const int tid  = threadIdx.x;
    const int lane = tid & 63;
    const int w    = tid >> 6;
    const int wm   = w >> 2;
    const int wn   = w & 3;

    // ---- staging geometry (pre-swizzled global source; linear LDS dest) ----
    const int lrow = lane >> 3;                       // 0..7
    const int csrc = ((lane & 7) ^ lrow) * 8;         // swizzled source col (elems)

    int tX[2], tY[2], ldsAX[2], ldsAY[2], ldsB0[2], ldsB1[2];
    #pragma unroll
    for (int c = 0; c < 2; ++c) {
        const int q = w * 2 + c;                      // 0..15
        tX[c] = q * 8 + (q & 8) * 8;                  // hX rows {0-63,128-191}
        tY[c] = tX[c] + 64;                           // hY rows {64-127,192-255}
        ldsAX[c] = tX[c] * BK;
        ldsAY[c] = tY[c] * BK;
        ldsB0[c] = (q * 8) * BK;
        ldsB1[c] = (128 + q * 8) * BK;
    }

    // ---- compute geometry ----
    const int frow = lane & 15;
    const int g8   = (lane >> 4) * 8;
    const int swc  = (frow & 7) << 3;
    const int ck0  = g8 ^ swc;
    const int ck1  = (32 + g8) ^ swc;
    const int arow = wm * 128 + frow;
    const int brow = wn * 64 + frow;
    const int crow = (lane >> 4) * 4;
    const int ccol = lane & 15;

    f32x4 acc[8][4];
    bf16x8 bk0[4], bk1[4];

    // cur / nxt pointer sets (per-lane bases at k-tile 0)
    const __bf16 *aXc[2], *aYc[2], *b0c[2], *b1c[2];
    const __bf16 *aXn[2], *aYn[2], *b0n[2], *b1n[2];

#define FILL_SET(aX_, aY_, b0_, b1_, row0v, rowsv, ev) { \
    _Pragma("unroll") for (int c = 0; c < 2; ++c) { \
        int rX = tX[c] + lrow; rX = (rX < (rowsv)) ? rX : 0; \
        int rY = tY[c] + lrow; rY = (rY < (rowsv)) ? rY : 0; \
        aX_[c] = A + (size_t)((row0v) + rX) * KDIM + csrc; \
        aY_[c] = A + (size_t)((row0v) + rY) * KDIM + csrc; \
        b0_[c] = W + (size_t)((ev) * NDIM + col0 + (w * 2 + c) * 8 + lrow) * KDIM + csrc; \
        b1_[c] = W + (size_t)((ev) * NDIM + col0 + 128 + (w * 2 + c) * 8 + lrow) * KDIM + csrc; \
    } }

#define RD_B(p) { _Pragma("unroll") for (int n = 0; n < 4; ++n) { \
        bk0[n] = *(const bf16x8*)&Bs[p][(brow + n * 16) * BK + ck0]; \
        bk1[n] = *(const bf16x8*)&Bs[p][(brow + n * 16) * BK + ck1]; } }

#define PHASE(p, j, STAGE) { \
    bf16x8 a00 = *(const bf16x8*)&As[p][(arow + (2 * (j)) * 16) * BK + ck0]; \
    bf16x8 a01 = *(const bf16x8*)&As[p][(arow + (2 * (j)) * 16) * BK + ck1]; \
    bf16x8 a10 = *(const bf16x8*)&As[p][(arow + (2 * (j) + 1) * 16) * BK + ck0]; \
    bf16x8 a11 = *(const bf16x8*)&As[p][(arow + (2 * (j) + 1) * 16) * BK + ck1]; \
    STAGE; \
    __builtin_amdgcn_s_barrier(); \
    asm volatile("s_waitcnt lgkmcnt(0)" ::: "memory"); \
    __builtin_amdgcn_s_setprio(1); \
    _Pragma("unroll") for (int n = 0; n < 4; ++n) { \
        acc[2 * (j)][n]     = __builtin_amdgcn_mfma_f32_16x16x32_bf16(a00, bk0[n], acc[2 * (j)][n], 0, 0, 0); \
        acc[2 * (j) + 1][n] = __builtin_amdgcn_mfma_f32_16x16x32_bf16(a10, bk0[n], acc[2 * (j) + 1][n], 0, 0, 0); \
    } \
    _Pragma("unroll") for (int n = 0; n < 4; ++n) { \
        acc[2 * (j)][n]     = __builtin_amdgcn_mfma_f32_16x16x32_bf16(a01, bk1[n], acc[2 * (j)][n], 0, 0, 0); \
        acc[2 * (j) + 1][n] = __builtin_amdgcn_mfma_f32_16x16x32_bf16(a11, bk1[n], acc[2 * (j) + 1][n], 0, 0, 0); \
    } \
    __builtin_amdgcn_s_setprio(0); }

// stage-address selectors: pass cur-array and nxt-array explicitly (no ## pasting).
// group-a = cur k-tile s2, else nxt kt0; group-b = cur s3, else nxt kt1.
#define PSA(Pc, Pn, c) ((i < 15) ? (Pc)[c] + s2o : (Pn)[c])
#define PSB(Pc, Pn, c) ((i < 15) ? (Pc)[c] + s3o : (Pn)[c] + BK)

    bool first = true;

    #pragma unroll 1
    for (int t = 0;; ++t) {
        const int mt = t * 8 + xslot;
        if (mt >= NMT) break;

        // ---- cur tile geometry ----
        int e = 0;
        #pragma unroll
        for (int i = 1; i < 8; ++i) e += (mt >= tstart[i]) ? 1 : 0;
        const int row0 = offs[e] + (mt - tstart[e]) * BM;
        int rows = offs[e + 1] - row0;
        if (rows > BM) rows = BM;
        FILL_SET(aXc, aYc, b0c, b1c, row0, rows, e);

        // ---- nxt tile geometry (clamped to cur on last tile) ----
        int mtn = mt + 8;
        if (mtn >= NMT) mtn = mt;
        int en = 0;
        #pragma unroll
        for (int i = 1; i < 8; ++i) en += (mtn >= tstart[i]) ? 1 : 0;
        const int row0n = offs[en] + (mtn - tstart[en]) * BM;
        int rowsn = offs[en + 1] - row0n;
        if (rowsn > BM) rowsn = BM;
        FILL_SET(aXn, aYn, b0n, b1n, row0n, rowsn, en);

        #pragma unroll
        for (int m = 0; m < 8; ++m)
            #pragma unroll
            for (int n = 0; n < 4; ++n)
                acc[m][n] = (f32x4){0.f, 0.f, 0.f, 0.f};

        if (first) {
            first = false;
            // prologue: cur kt0 full -> buf0; kt1 B0,B1,AX -> buf1
            #pragma unroll
            for (int c = 0; c < 2; ++c) {
                gload_lds16(aXc[c], &As[0][ldsAX[c]]);
                gload_lds16(aYc[c], &As[0][ldsAY[c]]);
            }
            #pragma unroll
            for (int c = 0; c < 2; ++c) {
                gload_lds16(b0c[c], &Bs[0][ldsB0[c]]);
                gload_lds16(b1c[c], &Bs[0][ldsB1[c]]);
            }
            #pragma unroll
            for (int c = 0; c < 2; ++c) {
                gload_lds16(b0c[c] + BK, &Bs[1][ldsB0[c]]);
                gload_lds16(b1c[c] + BK, &Bs[1][ldsB1[c]]);
            }
            #pragma unroll
            for (int c = 0; c < 2; ++c)
                gload_lds16(aXc[c] + BK, &As[1][ldsAX[c]]);
            asm volatile("s_waitcnt vmcnt(6)" ::: "memory");
            __builtin_amdgcn_s_barrier();
        }

        #pragma unroll 1
        for (int i = 0; i < 16; ++i) {
            const int t1o = (2 * i + 1) * BK;
            const int s2o = (2 * i + 2) * BK;
            const int s3o = (2 * i + 3) * BK;

            RD_B(0);
            PHASE(0, 0, { gload_lds16(aYc[0] + t1o, &As[1][ldsAY[0]]);
                          gload_lds16(aYc[1] + t1o, &As[1][ldsAY[1]]); });
            PHASE(0, 1, { gload_lds16(PSA(b0c, b0n, 0), &Bs[0][ldsB0[0]]);
                          gload_lds16(PSA(b0c, b0n, 1), &Bs[0][ldsB0[1]]); });
            PHASE(0, 2, { gload_lds16(PSA(b1c, b1n, 0), &Bs[0][ldsB1[0]]);
                          gload_lds16(PSA(b1c, b1n, 1), &Bs[0][ldsB1[1]]); });
            PHASE(0, 3, { gload_lds16(PSA(aXc, aXn, 0), &As[0][ldsAX[0]]);
                          gload_lds16(PSA(aXc, aXn, 1), &As[0][ldsAX[1]]);
                          asm volatile("s_waitcnt vmcnt(6)" ::: "memory"); });

            RD_B(1);
            PHASE(1, 0, { gload_lds16(PSA(aYc, aYn, 0), &As[0][ldsAY[0]]);
                          gload_lds16(PSA(aYc, aYn, 1), &As[0][ldsAY[1]]); });
            PHASE(1, 1, { gload_lds16(PSB(b0c, b0n, 0), &Bs[1][ldsB0[0]]);
                          gload_lds16(PSB(b0c, b0n, 1), &Bs[1][ldsB0[1]]); });
            PHASE(1, 2, { gload_lds16(PSB(b1c, b1n, 0), &Bs[1][ldsB1[0]]);
                          gload_lds16(PSB(b1c, b1n, 1), &Bs[1][ldsB1[1]]); });
            PHASE(1, 3, { gload_lds16(PSB(aXc, aXn, 0), &As[1][ldsAX[0]]);
                          gload_lds16(PSB(aXc, aXn, 1), &As[1][ldsAX[1]]);
                          asm volatile("s_waitcnt vmcnt(6)" ::: "memory"); });
        }

        // ---- epilogue for cur tile (C/D layout col=lane&15, row=(lane>>4)*4+reg) ----
        #pragma unroll
        for (int m = 0; m < 8; ++m) {
            #pragma unroll
            for (int j2 = 0; j2 < 4; ++j2) {
                const int r = wm * 128 + m * 16 + crow + j2;
                if (r < rows) {
                    float* dst = C + (size_t)(row0 + r) * NDIM + col0 + wn * 64 + ccol;
                    #pragma unroll
                    for (int n = 0; n < 4; ++n)
                        dst[n * 16] = acc[m][n][j2];
                }
            }
        }
    }
#undef FILL_SET
#undef RD_B
#undef PHASE
#undef PSA
#undef PSB
}

// ---------------- fallback (fused f32->bf16 staging) if ws too small ----------------
__global__ __launch_bounds__(256) void moe_gemm_f32(
    const float* __restrict__ A, const float* __restrict__ W, float* __restrict__ C)
{
    __shared__ __bf16 Asb[128][64];
    __shared__ __bf16 Bsb[128][64];

    const int tstart[9] = {0, 24, 64, 96, 112, 159, 191, 228, 260};
    const int offs[9]   = {0, 3000, 8000, 12096, 14144, 20144, 24144, 28768, 32768};

    const int mt = blockIdx.y;
    int e = 0;
    #pragma unroll
    for (int i = 1; i < 8; ++i) e += (mt >= tstart[i]) ? 1 : 0;
    const int row0 = offs[e] + (mt - tstart[e]) * 128;
    int rows = offs[e + 1] - row0;
    if (rows > 128) rows = 128;
    const int col0 = blockIdx.x * 128;

    const float* __restrict__ Abase = A + (size_t)row0 * KDIM;
    const float* __restrict__ Wbase = W + ((size_t)e * NDIM + (size_t)col0) * KDIM;

    const int tid  = threadIdx.x;
    const int lane = tid & 63;
    const int wid  = tid >> 6;
    const int wr   = (wid >> 1) * 64;
    const int wc   = (wid & 1) * 64;
    const int srow = tid >> 2;
    const int scol = (tid & 3) * 16;

    f32x4 acc[4][4];
    #pragma unroll
    for (int m = 0; m < 4; ++m)
        #pragma unroll
        for (int n = 0; n < 4; ++n)
            acc[m][n] = (f32x4){0.f, 0.f, 0.f, 0.f};
    const f32x4 fzero = (f32x4){0.f, 0.f, 0.f, 0.f};

    for (int k0 = 0; k0 < KDIM; k0 += 64) {
        __syncthreads();
        #pragma unroll
        for (int rr = 0; rr < 2; ++rr) {
            const int r = srow + rr * 64;
            {
                const bool valid = (r < rows);
                const float* pa = Abase + (size_t)r * KDIM + k0 + scol;
                f32x4 v[4];
                #pragma unroll
                for (int i = 0; i < 4; ++i) v[i] = valid ? *(const f32x4*)(pa + 4 * i) : fzero;
                bf16x8 h0, h1;
                #pragma unroll
                for (int i = 0; i < 8; ++i) {
                    h0[i] = (__bf16)v[i >> 2][i & 3];
                    h1[i] = (__bf16)v[2 + (i >> 2)][i & 3];
                }
                *((bf16x8*)&Asb[r][scol]) = h0;
                *((bf16x8*)&Asb[r][scol + 8]) = h1;
            }
            {
                const float* pb = Wbase + (size_t)r * KDIM + k0 + scol;
                f32x4 v[4];
                #pragma unroll
                for (int i = 0; i < 4; ++i) v[i] = *(const f32x4*)(pb + 4 * i);
                bf16x8 h0, h1;
                #pragma unroll
                for (int i = 0; i < 8; ++i) {
                    h0[i] = (__bf16)v[i >> 2][i & 3];
                    h1[i] = (__bf16)v[2 + (i >> 2)][i & 3];
                }
                *((bf16x8*)&Bsb[r][scol]) = h0;
                *((bf16x8*)&Bsb[r][scol + 8]) = h1;
            }
        }
        __syncthreads();
        #pragma unroll
        for (int ks = 0; ks < 2; ++ks) {
            const int kb = ks * 32 + (lane >> 4) * 8;
            bf16x8 af[4], bfr[4];
            #pragma unroll
            for (int m = 0; m < 4; ++m)
                af[m] = *((const bf16x8*)&Asb[wr + m * 16 + (lane & 15)][kb]);
            #pragma unroll
            for (int n = 0; n < 4; ++n)
                bfr[n] = *((const bf16x8*)&Bsb[wc + n * 16 + (lane & 15)][kb]);
            #pragma unroll
            for (int m = 0; m < 4; ++m)
                #pragma unroll
                for (int n = 0; n < 4; ++n)
                    acc[m][n] = __builtin_amdgcn_mfma_f32_16x16x32_bf16(
                        af[m], bfr[n], acc[m][n], 0, 0, 0);
        }
    }

    const int crow = (lane >> 4) * 4;
    const int ccol = lane & 15;
    #pragma unroll
    for (int m = 0; m < 4; ++m) {
        #pragma unroll
        for (int j = 0; j < 4; ++j) {
            const int r = wr + m * 16 + crow + j;
            if (r < rows) {
                float* dst = C + (size_t)(row0 + r) * NDIM + col0 + wc + ccol;
                #pragma unroll
                for (int n = 0; n < 4; ++n)
                    dst[n * 16] = acc[m][n][j];
            }
        }
    }
}

extern "C" void kernel_launch(void* const* d_in, const int* in_sizes, int n_in,
                              void* d_out, int out_size, void* d_ws, size_t ws_size,
                              hipStream_t stream) {
    const float* A = (const float*)d_in[0];
    const float* W = (const float*)d_in[1];
    float* C = (float*)d_out;

    const size_t nA = (size_t)MTOT * KDIM;
    const size_t nW = (size_t)8 * NDIM * KDIM;
    const size_t WS_NEED = (nA + nW) * 2;

    if (ws_size >= WS_NEED) {
        __bf16* Abf = (__bf16*)d_ws;
        __bf16* Wbf = (__bf16*)((char*)d_ws + nA * 2);
        hipLaunchKernelGGL(convert_f32_bf16, dim3(2048), dim3(256), 0, stream,
                           A, Abf, (int)(nA / 8));
        hipLaunchKernelGGL(convert_f32_bf16, dim3(2048), dim3(256), 0, stream,
                           W, Wbf, (int)(nW / 8));
        hipLaunchKernelGGL(moe_gemm_pers, dim3(256), dim3(512), 0, stream,
                           Abf, Wbf, C);
    } else {
        hipLaunchKernelGGL(moe_gemm_f32, dim3(NDIM / 128, 260), dim3(256), 0, stream,
                           A, W, C);
    }
}

// Round 8
// 1263.092 us; speedup vs baseline: 1.3135x; 1.3135x over previous
//
#include <hip/hip_runtime.h>

typedef __bf16 bf16x8 __attribute__((ext_vector_type(8)));
typedef float  f32x4  __attribute__((ext_vector_type(4)));

#define KDIM 2048
#define NDIM 8192
#define MTOT 32768
#define BM 256
#define BN 256
#define BK 64
#define NT 32            // K-tiles
#define NMT 131          // grouped 256-row m-tiles
#define NWG (NMT * 32)

__device__ __forceinline__ void gload_lds16(const void* g, void* l) {
    __builtin_amdgcn_global_load_lds(
        (const __attribute__((address_space(1))) void*)g,
        (__attribute__((address_space(3))) void*)l, 16, 0, 0);
}

// ---------------- fp32 -> bf16 pre-pass ----------------
__global__ __launch_bounds__(256) void convert_f32_bf16(
    const float* __restrict__ src, __bf16* __restrict__ dst, int n8)
{
    const int stride = gridDim.x * blockDim.x;
    for (int i = blockIdx.x * blockDim.x + threadIdx.x; i < n8; i += stride) {
        const f32x4* p = (const f32x4*)(src + (size_t)i * 8);
        f32x4 a = p[0], b = p[1];
        bf16x8 h;
        #pragma unroll
        for (int j = 0; j < 4; ++j) { h[j] = (__bf16)a[j]; h[4 + j] = (__bf16)b[j]; }
        *(bf16x8*)(dst + (size_t)i * 8) = h;
    }
}

// ---------------- 256x256 merged-4-phase grouped GEMM ----------------
// Base = R5 (non-persistent, natural order, XOR-swizzle, vmcnt(6) ring).
// R8: merge phase pairs -> 4 barriers+lgkm waits per 2-k-tile iter (was 8).
// Stage redistribution (race-audited):
//   MP1 {AY(1,t1)}          MP2 {B0,B1,AX(0,s2)} + vmcnt(6)
//   MP3 {AY(0,s2)}          MP4 {B0,B1,AX(1,s3)} + vmcnt(6)
// Every LDS overwrite has a barrier between it and its last reader:
//   AX rows read in MP1/MP3 (j0,j1), staged MP2/MP4; AY rows read in
//   MP2/MP4 (j2,j3), staged MP3/next-MP1; B tiles pulled to regs by RD_B
//   one barrier before their overwrite phase. vmcnt(6) keeps exactly the
//   issuing phase's 6 loads -> drains the tile needed next.
__global__ void __launch_bounds__(512, 2) moe_gemm_4ph(
    const __bf16* __restrict__ A,   // [32768][2048] bf16
    const __bf16* __restrict__ W,   // [8][8192][2048] bf16
    float* __restrict__ C)          // [32768][8192] fp32
{
    __shared__ __bf16 As[2][BM * BK];   // 2 x 32 KiB
    __shared__ __bf16 Bs[2][BN * BK];   // 2 x 32 KiB

    const int tstart[9] = {0, 12, 32, 48, 56, 80, 96, 115, 131};
    const int offs[9]   = {0, 3000, 8000, 12096, 14144, 20144, 24144, 28768, 32768};

    const int bid = blockIdx.x;
    const int mt = bid >> 5;          // natural order, nt fastest (L3-friendly)
    const int nt = bid & 31;

    int e = 0;
    #pragma unroll
    for (int i = 1; i < 8; ++i) e += (mt >= tstart[i]) ? 1 : 0;
    const int row0 = offs[e] + (mt - tstart[e]) * BM;
    int rows = offs[e + 1] - row0;
    if (rows > BM) rows = BM;
    const int col0 = nt * BN;

    const int tid  = threadIdx.x;
    const int lane = tid & 63;
    const int w    = tid >> 6;
    const int wm   = w >> 2;          // 0..1
    const int wn   = w & 3;           // 0..3

    // ---- staging geometry (pre-swizzled global source; linear LDS dest) ----
    const int lrow = lane >> 3;                       // 0..7
    const int csrc = ((lane & 7) ^ lrow) * 8;         // swizzled source col (elems)

    const __bf16 *aX[2], *aY[2], *b0[2], *b1[2];
    int ldsAX[2], ldsAY[2], ldsB0[2], ldsB1[2];
    #pragma unroll
    for (int c = 0; c < 2; ++c) {
        const int q  = w * 2 + c;                     // 0..15
        const int tX = q * 8 + (q & 8) * 8;           // hX rows {0-63,128-191}
        const int tY = tX + 64;                       // hY rows {64-127,192-255}
        int rX = tX + lrow; rX = (rX < rows) ? rX : 0;   // clamp: never stored
        int rY = tY + lrow; rY = (rY < rows) ? rY : 0;
        aX[c] = A + (size_t)(row0 + rX) * KDIM + csrc;
        aY[c] = A + (size_t)(row0 + rY) * KDIM + csrc;
        b0[c] = W + (size_t)(e * NDIM + col0 + q * 8 + lrow) * KDIM + csrc;
        b1[c] = W + (size_t)(e * NDIM + col0 + 128 + q * 8 + lrow) * KDIM + csrc;
        ldsAX[c] = tX * BK;
        ldsAY[c] = tY * BK;
        ldsB0[c] = (q * 8) * BK;
        ldsB1[c] = (128 + q * 8) * BK;
    }

#define STAGE_AX(p, o) { gload_lds16(aX[0] + (o), &As[p][ldsAX[0]]); \
                         gload_lds16(aX[1] + (o), &As[p][ldsAX[1]]); }
#define STAGE_AY(p, o) { gload_lds16(aY[0] + (o), &As[p][ldsAY[0]]); \
                         gload_lds16(aY[1] + (o), &As[p][ldsAY[1]]); }
#define STAGE_B0(p, o) { gload_lds16(b0[0] + (o), &Bs[p][ldsB0[0]]); \
                         gload_lds16(b0[1] + (o), &Bs[p][ldsB0[1]]); }
#define STAGE_B1(p, o) { gload_lds16(b1[0] + (o), &Bs[p][ldsB1[0]]); \
                         gload_lds16(b1[1] + (o), &Bs[p][ldsB1[1]]); }

    // ---- compute geometry ----
    const int frow = lane & 15;
    const int g8   = (lane >> 4) * 8;
    const int swc  = (frow & 7) << 3;
    const int ck0  = g8 ^ swc;
    const int ck1  = (32 + g8) ^ swc;
    const int arow = wm * 128 + frow;
    const int brow = wn * 64 + frow;

    f32x4 acc[8][4];
    #pragma unroll
    for (int m = 0; m < 8; ++m)
        #pragma unroll
        for (int n = 0; n < 4; ++n)
            acc[m][n] = (f32x4){0.f, 0.f, 0.f, 0.f};

    bf16x8 bk0[4], bk1[4];

#define RD_B(p) { _Pragma("unroll") for (int n = 0; n < 4; ++n) { \
        bk0[n] = *(const bf16x8*)&Bs[p][(brow + n * 16) * BK + ck0]; \
        bk1[n] = *(const bf16x8*)&Bs[p][(brow + n * 16) * BK + ck1]; } }

// merged phase h (h=0: m-frags 0..3 / rows 0-63; h=1: m-frags 4..7 / rows 64-127
// of the wave's 128-row half). 8 ds_read_b128, stage group, optional vmcnt(6),
// ONE barrier, lgkmcnt(0), 32 MFMA (16 indep k0-half, then 16 k1-half).
#define MPHASE(p, h, STAGE, DOVM) { \
    bf16x8 av0[4], av1[4]; \
    _Pragma("unroll") for (int mm = 0; mm < 4; ++mm) { \
        av0[mm] = *(const bf16x8*)&As[p][(arow + (4 * (h) + mm) * 16) * BK + ck0]; \
        av1[mm] = *(const bf16x8*)&As[p][(arow + (4 * (h) + mm) * 16) * BK + ck1]; \
    } \
    STAGE; \
    if (DOVM) { asm volatile("s_waitcnt vmcnt(6)" ::: "memory"); } \
    __builtin_amdgcn_s_barrier(); \
    asm volatile("s_waitcnt lgkmcnt(0)" ::: "memory"); \
    __builtin_amdgcn_s_setprio(1); \
    _Pragma("unroll") for (int n = 0; n < 4; ++n) \
        _Pragma("unroll") for (int mm = 0; mm < 4; ++mm) \
            acc[4 * (h) + mm][n] = __builtin_amdgcn_mfma_f32_16x16x32_bf16( \
                av0[mm], bk0[n], acc[4 * (h) + mm][n], 0, 0, 0); \
    _Pragma("unroll") for (int n = 0; n < 4; ++n) \
        _Pragma("unroll") for (int mm = 0; mm < 4; ++mm) \
            acc[4 * (h) + mm][n] = __builtin_amdgcn_mfma_f32_16x16x32_bf16( \
                av1[mm], bk1[n], acc[4 * (h) + mm][n], 0, 0, 0); \
    __builtin_amdgcn_s_setprio(0); }

    // ---- prologue: 7 halves (14 loads/wave), drain to 6 = buf1's B0,B1,AX ----
    STAGE_AX(0, 0); STAGE_AY(0, 0); STAGE_B0(0, 0); STAGE_B1(0, 0);
    STAGE_B0(1, BK); STAGE_B1(1, BK); STAGE_AX(1, BK);
    asm volatile("s_waitcnt vmcnt(6)" ::: "memory");
    __builtin_amdgcn_s_barrier();

    // ---- main loop: 16 iterations x 2 K-tiles ----
    #pragma unroll 1
    for (int i = 0; i < 16; ++i) {
        const int t1o = (2 * i + 1) * BK;
        int s2 = 2 * i + 2; if (s2 > NT - 1) s2 = NT - 1;   // clamped restage:
        int s3 = 2 * i + 3; if (s3 > NT - 1) s3 = NT - 1;   // same bytes, benign
        const int s2o = s2 * BK;
        const int s3o = s3 * BK;

        RD_B(0);
        MPHASE(0, 0, { STAGE_AY(1, t1o); }, 0);
        MPHASE(0, 1, { STAGE_B0(0, s2o); STAGE_B1(0, s2o); STAGE_AX(0, s2o); }, 1);

        RD_B(1);
        MPHASE(1, 0, { STAGE_AY(0, s2o); }, 0);
        MPHASE(1, 1, { STAGE_B0(1, s3o); STAGE_B1(1, s3o); STAGE_AX(1, s3o); }, 1);
    }

    // ---- epilogue: C/D layout col=lane&15, row=(lane>>4)*4+reg ----
    const int crow = (lane >> 4) * 4;
    const int ccol = lane & 15;
    #pragma unroll
    for (int m = 0; m < 8; ++m) {
        #pragma unroll
        for (int j2 = 0; j2 < 4; ++j2) {
            const int r = wm * 128 + m * 16 + crow + j2;
            if (r < rows) {
                float* dst = C + (size_t)(row0 + r) * NDIM + col0 + wn * 64 + ccol;
                #pragma unroll
                for (int n = 0; n < 4; ++n)
                    dst[n * 16] = acc[m][n][j2];
            }
        }
    }
#undef STAGE_AX
#undef STAGE_AY
#undef STAGE_B0
#undef STAGE_B1
#undef RD_B
#undef MPHASE
}

// ---------------- fallback (fused f32->bf16 staging) if ws too small ----------------
__global__ __launch_bounds__(256) void moe_gemm_f32(
    const float* __restrict__ A, const float* __restrict__ W, float* __restrict__ C)
{
    __shared__ __bf16 Asb[128][64];
    __shared__ __bf16 Bsb[128][64];

    const int tstart[9] = {0, 24, 64, 96, 112, 159, 191, 228, 260};
    const int offs[9]   = {0, 3000, 8000, 12096, 14144, 20144, 24144, 28768, 32768};

    const int mt = blockIdx.y;
    int e = 0;
    #pragma unroll
    for (int i = 1; i < 8; ++i) e += (mt >= tstart[i]) ? 1 : 0;
    const int row0 = offs[e] + (mt - tstart[e]) * 128;
    int rows = offs[e + 1] - row0;
    if (rows > 128) rows = 128;
    const int col0 = blockIdx.x * 128;

    const float* __restrict__ Abase = A + (size_t)row0 * KDIM;
    const float* __restrict__ Wbase = W + ((size_t)e * NDIM + (size_t)col0) * KDIM;

    const int tid  = threadIdx.x;
    const int lane = tid & 63;
    const int wid  = tid >> 6;
    const int wr   = (wid >> 1) * 64;
    const int wc   = (wid & 1) * 64;
    const int srow = tid >> 2;
    const int scol = (tid & 3) * 16;

    f32x4 acc[4][4];
    #pragma unroll
    for (int m = 0; m < 4; ++m)
        #pragma unroll
        for (int n = 0; n < 4; ++n)
            acc[m][n] = (f32x4){0.f, 0.f, 0.f, 0.f};
    const f32x4 fzero = (f32x4){0.f, 0.f, 0.f, 0.f};

    for (int k0 = 0; k0 < KDIM; k0 += 64) {
        __syncthreads();
        #pragma unroll
        for (int rr = 0; rr < 2; ++rr) {
            const int r = srow + rr * 64;
            {
                const bool valid = (r < rows);
                const float* pa = Abase + (size_t)r * KDIM + k0 + scol;
                f32x4 v[4];
                #pragma unroll
                for (int i = 0; i < 4; ++i) v[i] = valid ? *(const f32x4*)(pa + 4 * i) : fzero;
                bf16x8 h0, h1;
                #pragma unroll
                for (int i = 0; i < 8; ++i) {
                    h0[i] = (__bf16)v[i >> 2][i & 3];
                    h1[i] = (__bf16)v[2 + (i >> 2)][i & 3];
                }
                *((bf16x8*)&Asb[r][scol]) = h0;
                *((bf16x8*)&Asb[r][scol + 8]) = h1;
            }
            {
                const float* pb = Wbase + (size_t)r * KDIM + k0 + scol;
                f32x4 v[4];
                #pragma unroll
                for (int i = 0; i < 4; ++i) v[i] = *(const f32x4*)(pb + 4 * i);
                bf16x8 h0, h1;
                #pragma unroll
                for (int i = 0; i < 8; ++i) {
                    h0[i] = (__bf16)v[i >> 2][i & 3];
                    h1[i] = (__bf16)v[2 + (i >> 2)][i & 3];
                }
                *((bf16x8*)&Bsb[r][scol]) = h0;
                *((bf16x8*)&Bsb[r][scol + 8]) = h1;
            }
        }
        __syncthreads();
        #pragma unroll
        for (int ks = 0; ks < 2; ++ks) {
            const int kb = ks * 32 + (lane >> 4) * 8;
            bf16x8 af[4], bfr[4];
            #pragma unroll
            for (int m = 0; m < 4; ++m)
                af[m] = *((const bf16x8*)&Asb[wr + m * 16 + (lane & 15)][kb]);
            #pragma unroll
            for (int n = 0; n < 4; ++n)
                bfr[n] = *((const bf16x8*)&Bsb[wc + n * 16 + (lane & 15)][kb]);
            #pragma unroll
            for (int m = 0; m < 4; ++m)
                #pragma unroll
                for (int n = 0; n < 4; ++n)
                    acc[m][n] = __builtin_amdgcn_mfma_f32_16x16x32_bf16(
                        af[m], bfr[n], acc[m][n], 0, 0, 0);
        }
    }

    const int crow = (lane >> 4) * 4;
    const int ccol = lane & 15;
    #pragma unroll
    for (int m = 0; m < 4; ++m) {
        #pragma unroll
        for (int j = 0; j < 4; ++j) {
            const int r = wr + m * 16 + crow + j;
            if (r < rows) {
                float* dst = C + (size_t)(row0 + r) * NDIM + col0 + wc + ccol;
                #pragma unroll
                for (int n = 0; n < 4; ++n)
                    dst[n * 16] = acc[m][n][j];
            }
        }
    }
}

extern "C" void kernel_launch(void* const* d_in, const int* in_sizes, int n_in,
                              void* d_out, int out_size, void* d_ws, size_t ws_size,
                              hipStream_t stream) {
    const float* A = (const float*)d_in[0];
    const float* W = (const float*)d_in[1];
    float* C = (float*)d_out;

    const size_t nA = (size_t)MTOT * KDIM;
    const size_t nW = (size_t)8 * NDIM * KDIM;
    const size_t WS_NEED = (nA + nW) * 2;

    if (ws_size >= WS_NEED) {
        __bf16* Abf = (__bf16*)d_ws;
        __bf16* Wbf = (__bf16*)((char*)d_ws + nA * 2);
        hipLaunchKernelGGL(convert_f32_bf16, dim3(2048), dim3(256), 0, stream,
                           A, Abf, (int)(nA / 8));
        hipLaunchKernelGGL(convert_f32_bf16, dim3(2048), dim3(256), 0, stream,
                           W, Wbf, (int)(nW / 8));
        hipLaunchKernelGGL(moe_gemm_4ph, dim3(NWG), dim3(512), 0, stream,
                           Abf, Wbf, C);
    } else {
        hipLaunchKernelGGL(moe_gemm_f32, dim3(NDIM / 128, 260), dim3(256), 0, stream,
                           A, W, C);
    }
}